// Round 1
// baseline (112.375 us; speedup 1.0000x reference)
//
#include <hip/hip_runtime.h>
#include <hip/hip_bf16.h>

#define BSTRIDE 24

// Per-box preprocessing: store
//  o[0..8]  = R rows (row-major, 3x3)
//  o[9..11] = p0 = bbmin @ R + t   (transformed min corner)
//  o[12..20]= e_d rows = dims_d * R[d,:]  (d=0,1,2)
__global__ void pv_prep(const float* __restrict__ bb, const float* __restrict__ rot,
                        const float* __restrict__ tr, float* __restrict__ bx, int B) {
    int b = blockIdx.x * blockDim.x + threadIdx.x;
    if (b >= B) return;
    const float* s = bb + b * 6;
    const float* R = rot + b * 9;
    const float* t = tr + b * 3;
    float* o = bx + b * BSTRIDE;
    float mnx = s[0], mny = s[1], mnz = s[2];
    float dx = s[3], dy = s[4], dz = s[5];
#pragma unroll
    for (int e = 0; e < 3; e++) {
        float r0 = R[e], r1 = R[3 + e], r2 = R[6 + e];
        o[e]      = r0;
        o[3 + e]  = r1;
        o[6 + e]  = r2;
        o[9 + e]  = mnx * r0 + mny * r1 + mnz * r2 + t[e];
        o[12 + e] = dx * r0;
        o[15 + e] = dy * r1;
        o[18 + e] = dz * r2;
    }
}

__global__ __launch_bounds__(256) void pv_pairs(const float* __restrict__ bx,
                                                float* __restrict__ out, int B) {
    const int i = blockIdx.y;
    const int j = blockIdx.x * blockDim.x + threadIdx.x;
    float pen = 0.0f;
    if (j < B && j > i) {
        const float* bi = bx + i * BSTRIDE;
        const float* bj = bx + j * BSTRIDE;
        float Ri[9], Rj[9], pi[3], pj[3], ei[9], ej[9];
#pragma unroll
        for (int k = 0; k < 9; k++) {
            Ri[k] = bi[k];
            Rj[k] = bj[k];
            ei[k] = bi[12 + k];
            ej[k] = bj[12 + k];
        }
#pragma unroll
        for (int k = 0; k < 3; k++) {
            pi[k] = bi[9 + k];
            pj[k] = bj[9 + k];
        }

        bool pass = true;
        float minov = __builtin_inff();

        const int CA[6] = {0, 0, 0, 1, 1, 2};
        const int CB[6] = {0, 1, 2, 1, 2, 2};

#pragma unroll
        for (int a = 0; a < 9; a++) {
            float ax, ay, az;
            bool valid = true;
            if (a < 3) {
                ax = Ri[a * 3 + 0];
                ay = Ri[a * 3 + 1];
                az = Ri[a * 3 + 2];
            } else {
                const int ra = CA[a - 3], rb = CB[a - 3];
                float ux = Ri[ra * 3 + 0], uy = Ri[ra * 3 + 1], uz = Ri[ra * 3 + 2];
                float vx = Rj[rb * 3 + 0], vy = Rj[rb * 3 + 1], vz = Rj[rb * 3 + 2];
                ax = uy * vz - uz * vy;
                ay = uz * vx - ux * vz;
                az = ux * vy - uy * vx;
                valid = (ax != 0.0f) || (ay != 0.0f) || (az != 0.0f);
            }
            if (valid) {
                // box i projection extent on axis
                float b1 = pi[0] * ax + pi[1] * ay + pi[2] * az;
                float lo1 = b1, hi1 = b1;
#pragma unroll
                for (int d = 0; d < 3; d++) {
                    float w = ei[d * 3 + 0] * ax + ei[d * 3 + 1] * ay + ei[d * 3 + 2] * az;
                    lo1 += fminf(w, 0.0f);
                    hi1 += fmaxf(w, 0.0f);
                }
                // box j projection extent on axis
                float b2 = pj[0] * ax + pj[1] * ay + pj[2] * az;
                float lo2 = b2, hi2 = b2;
#pragma unroll
                for (int d = 0; d < 3; d++) {
                    float w = ej[d * 3 + 0] * ax + ej[d * 3 + 1] * ay + ej[d * 3 + 2] * az;
                    lo2 += fminf(w, 0.0f);
                    hi2 += fmaxf(w, 0.0f);
                }
                float total = fmaxf(hi1, hi2) - fminf(lo1, lo2);
                float slen = (hi1 - lo1) + (hi2 - lo2);
                float ov = slen - total;              // overlap on this axis
                pass = pass && (ov > 0.0f);           // strict: total_len < sum_len
                minov = fminf(minov, ov);
            }
        }
        pen = pass ? minov : 0.0f;
    }

    // block reduction -> one atomicAdd per block
    __shared__ float sdata[256];
    const int tid = threadIdx.x;
    sdata[tid] = pen;
    __syncthreads();
#pragma unroll
    for (int s = 128; s > 0; s >>= 1) {
        if (tid < s) sdata[tid] += sdata[tid + s];
        __syncthreads();
    }
    if (tid == 0) atomicAdd(out, sdata[0]);
}

extern "C" void kernel_launch(void* const* d_in, const int* in_sizes, int n_in,
                              void* d_out, int out_size, void* d_ws, size_t ws_size,
                              hipStream_t stream) {
    const float* bb  = (const float*)d_in[0];   // [B,6]
    const float* rot = (const float*)d_in[1];   // [B,3,3]
    const float* tr  = (const float*)d_in[2];   // [B,1,3]
    float* out = (float*)d_out;                  // scalar
    const int B = in_sizes[0] / 6;

    float* bx = (float*)d_ws;                    // B * 24 floats

    hipMemsetAsync(out, 0, sizeof(float), stream);

    {
        dim3 grid((B + 255) / 256);
        dim3 block(256);
        pv_prep<<<grid, block, 0, stream>>>(bb, rot, tr, bx, B);
    }
    {
        dim3 grid((B + 255) / 256, B);
        dim3 block(256);
        pv_pairs<<<grid, block, 0, stream>>>(bx, out, B);
    }
}

// Round 4
// 76.242 us; speedup vs baseline: 1.4739x; 1.4739x over previous
//
#include <hip/hip_runtime.h>
#include <hip/hip_bf16.h>

#define NI 8  // i-values (pairs) per thread

// Compute per-box derived data from raw inputs:
//  R[9]  = rotation rows (row-major)
//  p[3]  = bbmin @ R + t  (transformed min corner)
//  e[9]  = rows e_d = dims_d * R[d,:]
__device__ __forceinline__ void load_box(const float* __restrict__ bb,
                                         const float* __restrict__ rot,
                                         const float* __restrict__ tr,
                                         int b, float* R, float* p, float* e) {
    const float* s = bb + b * 6;
    const float* r = rot + b * 9;
    const float* t = tr + b * 3;
    float mn0 = s[0], mn1 = s[1], mn2 = s[2];
    float d0 = s[3], d1 = s[4], d2 = s[5];
#pragma unroll
    for (int k = 0; k < 9; k++) R[k] = r[k];
#pragma unroll
    for (int k = 0; k < 3; k++) {
        p[k]     = mn0 * R[k] + mn1 * R[3 + k] + mn2 * R[6 + k] + t[k];
        e[k]     = d0 * R[k];
        e[3 + k] = d1 * R[3 + k];
        e[6 + k] = d2 * R[6 + k];
    }
}

// Interval overlap of the two boxes' projections on one axis.
// hi = s + h, lo = s - h with s = center proj, h = half extent (Σ|w_d|/2).
// ov = min(hi1,hi2) - max(lo1,lo2)  (== sum_len - total_len algebraically)
__device__ __forceinline__ float axis_overlap(float ax, float ay, float az,
                                              const float* pi, const float* ei,
                                              const float* pj, const float* ej) {
    float b1 = pi[0] * ax + pi[1] * ay + pi[2] * az;
    float u0 = ei[0] * ax + ei[1] * ay + ei[2] * az;
    float u1 = ei[3] * ax + ei[4] * ay + ei[5] * az;
    float u2 = ei[6] * ax + ei[7] * ay + ei[8] * az;
    float s1 = b1 + 0.5f * (u0 + u1 + u2);
    float h1 = 0.5f * (fabsf(u0) + fabsf(u1) + fabsf(u2));

    float b2 = pj[0] * ax + pj[1] * ay + pj[2] * az;
    float v0 = ej[0] * ax + ej[1] * ay + ej[2] * az;
    float v1 = ej[3] * ax + ej[4] * ay + ej[5] * az;
    float v2 = ej[6] * ax + ej[7] * ay + ej[8] * az;
    float s2 = b2 + 0.5f * (v0 + v1 + v2);
    float h2 = 0.5f * (fabsf(v0) + fabsf(v1) + fabsf(v2));

    return fminf(s1 + h1, s2 + h2) - fmaxf(s1 - h1, s2 - h2);
}

__global__ __launch_bounds__(256) void pv_pairs(const float* __restrict__ bb,
                                                const float* __restrict__ rot,
                                                const float* __restrict__ tr,
                                                float* __restrict__ partial, int B) {
    const int jc = blockIdx.x;          // j chunk of 256
    const int ic = blockIdx.y;          // i chunk of NI
    const int jbase = jc * 256;
    const int ibase = ic * NI;
    const int j = jbase + threadIdx.x;  // lane-varying, uniform-i loop below

    float pen = 0.0f;
    if (ibase < jbase + 256 && j < B) {  // block intersects the j>i triangle
        // j-side box: computed once, lives in registers for all NI pairs
        float Rj[9], pj[3], ej[9];
        load_box(bb, rot, tr, j, Rj, pj, ej);

#pragma unroll 2
        for (int ii = 0; ii < NI; ii++) {
            const int i = ibase + ii;
            if (i >= B) break;
            if (i >= j) continue;  // exec-mask; i is wave-uniform so loads stay scalar
            // i-side box: uniform -> s_load + uniform VALU
            float Ri[9], pi[3], ei[9];
            load_box(bb, rot, tr, i, Ri, pi, ei);

            bool pass = true;
            float minov = __builtin_inff();

            // 3 face axes of box i (first box; reference dedups the duplicate pass)
#pragma unroll
            for (int a = 0; a < 3; a++) {
                float ov = axis_overlap(Ri[a * 3], Ri[a * 3 + 1], Ri[a * 3 + 2],
                                        pi, ei, pj, ej);
                pass = pass && (ov > 0.0f);
                minov = fminf(minov, ov);
            }
            // 6 cross axes: (A,B) in {(0,0),(0,1),(0,2),(1,1),(1,2),(2,2)}
            const int CA[6] = {0, 0, 0, 1, 1, 2};
            const int CB[6] = {0, 1, 2, 1, 2, 2};
#pragma unroll
            for (int c = 0; c < 6; c++) {
                const int ra = CA[c], rb = CB[c];
                float ux = Ri[ra * 3], uy = Ri[ra * 3 + 1], uz = Ri[ra * 3 + 2];
                float vx = Rj[rb * 3], vy = Rj[rb * 3 + 1], vz = Rj[rb * 3 + 2];
                float ax = uy * vz - uz * vy;
                float ay = uz * vx - ux * vz;
                float az = ux * vy - uy * vx;
                if ((ax != 0.0f) || (ay != 0.0f) || (az != 0.0f)) {
                    float ov = axis_overlap(ax, ay, az, pi, ei, pj, ej);
                    pass = pass && (ov > 0.0f);
                    minov = fminf(minov, ov);
                }
            }
            pen += pass ? minov : 0.0f;
        }
    }

    // wave shfl reduce, then tiny LDS combine; one plain store per block (no atomics)
#pragma unroll
    for (int off = 32; off > 0; off >>= 1) pen += __shfl_down(pen, off);
    __shared__ float wsum[4];
    const int wid = threadIdx.x >> 6;
    if ((threadIdx.x & 63) == 0) wsum[wid] = pen;
    __syncthreads();
    if (threadIdx.x == 0)
        partial[blockIdx.y * gridDim.x + blockIdx.x] = wsum[0] + wsum[1] + wsum[2] + wsum[3];
}

__global__ __launch_bounds__(256) void pv_reduce(const float* __restrict__ partial,
                                                 float* __restrict__ out, int n) {
    float s = 0.0f;
    for (int k = threadIdx.x; k < n; k += 256) s += partial[k];
#pragma unroll
    for (int off = 32; off > 0; off >>= 1) s += __shfl_down(s, off);
    __shared__ float wsum[4];
    const int wid = threadIdx.x >> 6;
    if ((threadIdx.x & 63) == 0) wsum[wid] = s;
    __syncthreads();
    if (threadIdx.x == 0) out[0] = wsum[0] + wsum[1] + wsum[2] + wsum[3];
}

extern "C" void kernel_launch(void* const* d_in, const int* in_sizes, int n_in,
                              void* d_out, int out_size, void* d_ws, size_t ws_size,
                              hipStream_t stream) {
    const float* bb  = (const float*)d_in[0];   // [B,6]
    const float* rot = (const float*)d_in[1];   // [B,3,3]
    const float* tr  = (const float*)d_in[2];   // [B,1,3]
    float* out = (float*)d_out;                  // scalar
    const int B = in_sizes[0] / 6;

    float* partial = (float*)d_ws;

    const int gx = (B + 255) / 256;      // j chunks
    const int gy = (B + NI - 1) / NI;    // i chunks
    dim3 grid(gx, gy);
    dim3 block(256);
    pv_pairs<<<grid, block, 0, stream>>>(bb, rot, tr, partial, B);
    pv_reduce<<<1, 256, 0, stream>>>(partial, out, gx * gy);
}

// Round 5
// 70.539 us; speedup vs baseline: 1.5931x; 1.0809x over previous
//
#include <hip/hip_runtime.h>
#include <hip/hip_bf16.h>

#define NI 4    // i-values (pairs) per thread
#define JT 256  // j-lanes per block

// Per-box derived data:
//  R[9] = rotation rows (row-major)
//  p[3] = bbmin @ R + t  (transformed min corner)
//  e[9] = rows e_d = dims_d * R[d,:]
__device__ __forceinline__ void load_box(const float* __restrict__ bb,
                                         const float* __restrict__ rot,
                                         const float* __restrict__ tr,
                                         int b, float* R, float* p, float* e) {
    const float* s = bb + b * 6;
    const float* r = rot + b * 9;
    const float* t = tr + b * 3;
    float mn0 = s[0], mn1 = s[1], mn2 = s[2];
    float d0 = s[3], d1 = s[4], d2 = s[5];
#pragma unroll
    for (int k = 0; k < 9; k++) R[k] = r[k];
#pragma unroll
    for (int k = 0; k < 3; k++) {
        p[k]     = mn0 * R[k] + mn1 * R[3 + k] + mn2 * R[6 + k] + t[k];
        e[k]     = d0 * R[k];
        e[3 + k] = d1 * R[3 + k];
        e[6 + k] = d2 * R[6 + k];
    }
}

// Interval overlap of the two boxes' projections on one axis.
// ov = min(hi1,hi2) - max(lo1,lo2)  (== sum_len - total_len algebraically)
__device__ __forceinline__ float axis_overlap(float ax, float ay, float az,
                                              const float* pi, const float* ei,
                                              const float* pj, const float* ej) {
    float b1 = pi[0] * ax + pi[1] * ay + pi[2] * az;
    float u0 = ei[0] * ax + ei[1] * ay + ei[2] * az;
    float u1 = ei[3] * ax + ei[4] * ay + ei[5] * az;
    float u2 = ei[6] * ax + ei[7] * ay + ei[8] * az;
    float s1 = b1 + 0.5f * (u0 + u1 + u2);
    float h1 = 0.5f * (fabsf(u0) + fabsf(u1) + fabsf(u2));

    float b2 = pj[0] * ax + pj[1] * ay + pj[2] * az;
    float v0 = ej[0] * ax + ej[1] * ay + ej[2] * az;
    float v1 = ej[3] * ax + ej[4] * ay + ej[5] * az;
    float v2 = ej[6] * ax + ej[7] * ay + ej[8] * az;
    float s2 = b2 + 0.5f * (v0 + v1 + v2);
    float h2 = 0.5f * (fabsf(v0) + fabsf(v1) + fabsf(v2));

    return fminf(s1 + h1, s2 + h2) - fmaxf(s1 - h1, s2 - h2);
}

// Triangle-only grid: 1D blocks decode to (jc, ic); every block has work.
__global__ __launch_bounds__(JT) void pv_pairs(const float* __restrict__ bb,
                                               const float* __restrict__ rot,
                                               const float* __restrict__ tr,
                                               float* __restrict__ partial, int B) {
    const int icAll = (B + NI - 1) / NI;
    int bid = blockIdx.x;
    int jc = 0, base = 0, ic = 0;
    for (;; jc++) {  // gx is tiny (B/JT = 4); loop is a few SALU ops
        int icmax = min(((jc + 1) * JT + NI - 1) / NI, icAll);
        if (bid < base + icmax) { ic = bid - base; break; }
        base += icmax;
    }
    const int jbase = jc * JT;
    const int ibase = ic * NI;
    const int j = jbase + threadIdx.x;

    float pen = 0.0f;
    if (j < B) {
        // j-side box: computed once, register-resident for all NI pairs
        float Rj[9], pj[3], ej[9];
        load_box(bb, rot, tr, j, Rj, pj, ej);

#pragma unroll
        for (int ii = 0; ii < NI; ii++) {
            const int i = ibase + ii;
            if (i >= B) break;
            if (i >= j) continue;  // exec-mask; i is wave-uniform so loads stay scalar
            float Ri[9], pi[3], ei[9];
            load_box(bb, rot, tr, i, Ri, pi, ei);

            bool pass = true;
            float minov = __builtin_inff();

            // 3 face axes of box i (reference dedups its duplicated first-box pass)
#pragma unroll
            for (int a = 0; a < 3; a++) {
                float ov = axis_overlap(Ri[a * 3], Ri[a * 3 + 1], Ri[a * 3 + 2],
                                        pi, ei, pj, ej);
                pass = pass && (ov > 0.0f);
                minov = fminf(minov, ov);
            }
            // 6 cross axes: (A,B) in {(0,0),(0,1),(0,2),(1,1),(1,2),(2,2)}
            const int CA[6] = {0, 0, 0, 1, 1, 2};
            const int CB[6] = {0, 1, 2, 1, 2, 2};
#pragma unroll
            for (int c = 0; c < 6; c++) {
                const int ra = CA[c], rb = CB[c];
                float ux = Ri[ra * 3], uy = Ri[ra * 3 + 1], uz = Ri[ra * 3 + 2];
                float vx = Rj[rb * 3], vy = Rj[rb * 3 + 1], vz = Rj[rb * 3 + 2];
                float ax = uy * vz - uz * vy;
                float ay = uz * vx - ux * vz;
                float az = ux * vy - uy * vx;
                if ((ax != 0.0f) || (ay != 0.0f) || (az != 0.0f)) {
                    float ov = axis_overlap(ax, ay, az, pi, ei, pj, ej);
                    pass = pass && (ov > 0.0f);
                    minov = fminf(minov, ov);
                }
            }
            pen += pass ? minov : 0.0f;
        }
    }

    // wave shfl reduce, tiny LDS combine, one plain store per block (no atomics)
#pragma unroll
    for (int off = 32; off > 0; off >>= 1) pen += __shfl_down(pen, off);
    __shared__ float wsum[JT / 64];
    const int wid = threadIdx.x >> 6;
    if ((threadIdx.x & 63) == 0) wsum[wid] = pen;
    __syncthreads();
    if (threadIdx.x == 0) {
        float s = 0.0f;
#pragma unroll
        for (int w = 0; w < JT / 64; w++) s += wsum[w];
        partial[blockIdx.x] = s;
    }
}

__global__ __launch_bounds__(256) void pv_reduce(const float* __restrict__ partial,
                                                 float* __restrict__ out, int n) {
    float s = 0.0f;
    for (int k = threadIdx.x; k < n; k += 256) s += partial[k];
#pragma unroll
    for (int off = 32; off > 0; off >>= 1) s += __shfl_down(s, off);
    __shared__ float wsum[4];
    const int wid = threadIdx.x >> 6;
    if ((threadIdx.x & 63) == 0) wsum[wid] = s;
    __syncthreads();
    if (threadIdx.x == 0) out[0] = wsum[0] + wsum[1] + wsum[2] + wsum[3];
}

extern "C" void kernel_launch(void* const* d_in, const int* in_sizes, int n_in,
                              void* d_out, int out_size, void* d_ws, size_t ws_size,
                              hipStream_t stream) {
    const float* bb  = (const float*)d_in[0];   // [B,6]
    const float* rot = (const float*)d_in[1];   // [B,3,3]
    const float* tr  = (const float*)d_in[2];   // [B,1,3]
    float* out = (float*)d_out;                  // scalar
    const int B = in_sizes[0] / 6;

    float* partial = (float*)d_ws;

    // count active (triangle) tiles: jc in [0, gx), ic < min(((jc+1)*JT+NI-1)/NI, ceil(B/NI))
    const int gx = (B + JT - 1) / JT;
    const int icAll = (B + NI - 1) / NI;
    int total = 0;
    for (int jc = 0; jc < gx; jc++) {
        int icmax = ((jc + 1) * JT + NI - 1) / NI;
        total += (icmax < icAll) ? icmax : icAll;
    }

    pv_pairs<<<dim3(total), dim3(JT), 0, stream>>>(bb, rot, tr, partial, B);
    pv_reduce<<<1, 256, 0, stream>>>(partial, out, total);
}

// Round 6
// 68.487 us; speedup vs baseline: 1.6408x; 1.0300x over previous
//
#include <hip/hip_runtime.h>
#include <hip/hip_bf16.h>

#define NI 2    // i-values (pairs) per thread
#define JT 256  // j-lanes per block

// Per-box derived data:
//  R[9] = rotation rows (row-major)
//  c[3] = box center transformed: (mn + 0.5*dims) @ R + t
//  e[9] = rows e_d = dims_d * R[d,:]
__device__ __forceinline__ void load_box(const float* __restrict__ bb,
                                         const float* __restrict__ rot,
                                         const float* __restrict__ tr,
                                         int b, float* R, float* c, float* e) {
    const float* s = bb + b * 6;
    const float* r = rot + b * 9;
    const float* t = tr + b * 3;
    float d0 = s[3], d1 = s[4], d2 = s[5];
    float a0 = s[0] + 0.5f * d0, a1 = s[1] + 0.5f * d1, a2 = s[2] + 0.5f * d2;
#pragma unroll
    for (int k = 0; k < 9; k++) R[k] = r[k];
#pragma unroll
    for (int k = 0; k < 3; k++) {
        c[k]     = a0 * R[k] + a1 * R[3 + k] + a2 * R[6 + k] + t[k];
        e[k]     = d0 * R[k];
        e[3 + k] = d1 * R[3 + k];
        e[6 + k] = d2 * R[6 + k];
    }
}

// Interval overlap of the two boxes' projections on one axis.
// s = center proj, h = half extent; ov = min(hi1,hi2) - max(lo1,lo2)
// (identical to the reference's sum_len - total_len for ALL cases, incl. containment)
__device__ __forceinline__ float axis_overlap(float ax, float ay, float az,
                                              const float* ci, const float* ei,
                                              const float* cj, const float* ej) {
    float s1 = ci[0] * ax + ci[1] * ay + ci[2] * az;
    float u0 = ei[0] * ax + ei[1] * ay + ei[2] * az;
    float u1 = ei[3] * ax + ei[4] * ay + ei[5] * az;
    float u2 = ei[6] * ax + ei[7] * ay + ei[8] * az;
    float h1 = 0.5f * (fabsf(u0) + fabsf(u1) + fabsf(u2));

    float s2 = cj[0] * ax + cj[1] * ay + cj[2] * az;
    float v0 = ej[0] * ax + ej[1] * ay + ej[2] * az;
    float v1 = ej[3] * ax + ej[4] * ay + ej[5] * az;
    float v2 = ej[6] * ax + ej[7] * ay + ej[8] * az;
    float h2 = 0.5f * (fabsf(v0) + fabsf(v1) + fabsf(v2));

    return fminf(s1 + h1, s2 + h2) - fmaxf(s1 - h1, s2 - h2);
}

// Triangle-only grid: 1D blocks decode to (jc, ic); every block has work.
__global__ __launch_bounds__(JT) void pv_pairs(const float* __restrict__ bb,
                                               const float* __restrict__ rot,
                                               const float* __restrict__ tr,
                                               float* __restrict__ partial, int B) {
    const int icAll = (B + NI - 1) / NI;
    int bid = blockIdx.x;
    int jc = 0, base = 0, ic = 0;
    for (;; jc++) {  // gx is tiny (B/JT = 4); a few SALU ops
        int icmax = min(((jc + 1) * JT + NI - 1) / NI, icAll);
        if (bid < base + icmax) { ic = bid - base; break; }
        base += icmax;
    }
    const int jbase = jc * JT;
    const int ibase = ic * NI;
    const int j = jbase + threadIdx.x;

    float pen = 0.0f;
    if (j < B) {
        // j-side box: computed once, register-resident for all NI pairs
        float Rj[9], cj[3], ej[9];
        load_box(bb, rot, tr, j, Rj, cj, ej);

#pragma unroll
        for (int ii = 0; ii < NI; ii++) {
            const int i = ibase + ii;
            if (i >= B) break;
            if (i >= j) continue;  // exec-mask; i wave-uniform -> scalar loads
            float Ri[9], ci[3], ei[9];
            load_box(bb, rot, tr, i, Ri, ci, ei);

            bool pass = true;
            float minov = __builtin_inff();

            // 3 face axes of box i (reference dedups its duplicated first-box pass)
#pragma unroll
            for (int a = 0; a < 3; a++) {
                float ov = axis_overlap(Ri[a * 3], Ri[a * 3 + 1], Ri[a * 3 + 2],
                                        ci, ei, cj, ej);
                pass = pass && (ov > 0.0f);
                minov = fminf(minov, ov);
            }
            // 6 cross axes: (A,B) in {(0,0),(0,1),(0,2),(1,1),(1,2),(2,2)}
            const int CA[6] = {0, 0, 0, 1, 1, 2};
            const int CB[6] = {0, 1, 2, 1, 2, 2};
#pragma unroll
            for (int cc = 0; cc < 6; cc++) {
                const int ra = CA[cc], rb = CB[cc];
                float ux = Ri[ra * 3], uy = Ri[ra * 3 + 1], uz = Ri[ra * 3 + 2];
                float vx = Rj[rb * 3], vy = Rj[rb * 3 + 1], vz = Rj[rb * 3 + 2];
                float ax = uy * vz - uz * vy;
                float ay = uz * vx - ux * vz;
                float az = ux * vy - uy * vx;
                if ((ax != 0.0f) || (ay != 0.0f) || (az != 0.0f)) {
                    float ov = axis_overlap(ax, ay, az, ci, ei, cj, ej);
                    pass = pass && (ov > 0.0f);
                    minov = fminf(minov, ov);
                }
            }
            pen += pass ? minov : 0.0f;
        }
    }

    // wave shfl reduce, tiny LDS combine, one plain store per block (no atomics)
#pragma unroll
    for (int off = 32; off > 0; off >>= 1) pen += __shfl_down(pen, off);
    __shared__ float wsum[JT / 64];
    const int wid = threadIdx.x >> 6;
    if ((threadIdx.x & 63) == 0) wsum[wid] = pen;
    __syncthreads();
    if (threadIdx.x == 0) {
        float s = 0.0f;
#pragma unroll
        for (int w = 0; w < JT / 64; w++) s += wsum[w];
        partial[blockIdx.x] = s;
    }
}

__global__ __launch_bounds__(256) void pv_reduce(const float* __restrict__ partial,
                                                 float* __restrict__ out, int n) {
    float s = 0.0f;
    for (int k = threadIdx.x; k < n; k += 256) s += partial[k];
#pragma unroll
    for (int off = 32; off > 0; off >>= 1) s += __shfl_down(s, off);
    __shared__ float wsum[4];
    const int wid = threadIdx.x >> 6;
    if ((threadIdx.x & 63) == 0) wsum[wid] = s;
    __syncthreads();
    if (threadIdx.x == 0) out[0] = wsum[0] + wsum[1] + wsum[2] + wsum[3];
}

extern "C" void kernel_launch(void* const* d_in, const int* in_sizes, int n_in,
                              void* d_out, int out_size, void* d_ws, size_t ws_size,
                              hipStream_t stream) {
    const float* bb  = (const float*)d_in[0];   // [B,6]
    const float* rot = (const float*)d_in[1];   // [B,3,3]
    const float* tr  = (const float*)d_in[2];   // [B,1,3]
    float* out = (float*)d_out;                  // scalar
    const int B = in_sizes[0] / 6;

    float* partial = (float*)d_ws;

    // count active (triangle) tiles
    const int gx = (B + JT - 1) / JT;
    const int icAll = (B + NI - 1) / NI;
    int total = 0;
    for (int jc = 0; jc < gx; jc++) {
        int icmax = ((jc + 1) * JT + NI - 1) / NI;
        total += (icmax < icAll) ? icmax : icAll;
    }

    pv_pairs<<<dim3(total), dim3(JT), 0, stream>>>(bb, rot, tr, partial, B);
    pv_reduce<<<1, 256, 0, stream>>>(partial, out, total);
}